// Round 2
// baseline (250.883 us; speedup 1.0000x reference)
//
#include <hip/hip_runtime.h>
#include <hip/hip_bf16.h>

// Problem constants
#define Bb    32
#define CO    128
#define CI    128
#define HW    56
#define NPIX  3136   // 56*56
#define PH    58
#define PPIX  3364   // 58*58
#define NT    25     // ceil(3136/128)

typedef __bf16 bf16x8 __attribute__((ext_vector_type(8)));
typedef float  f32x4  __attribute__((ext_vector_type(4)));

// ---------------------------------------------------------------------------
// Prep 1 (coalesced): one thread per (b,co,ci); reads 9 contiguous floats from
// eps/psi/mu, writes wt[b][p][co][ci] (coalesced across ci per p).
// ---------------------------------------------------------------------------
__global__ void prep_weights(const float* __restrict__ eps,
                             const float* __restrict__ psi,
                             const float* __restrict__ mu,
                             __bf16* __restrict__ wt) {
  int idx = blockIdx.x * 256 + threadIdx.x;          // = (b*CO+co)*CI+ci
  int ci = idx & 127;
  int co = (idx >> 7) & 127;
  int b  = idx >> 14;
  const float* e  = eps + (size_t)idx * 9;           // eps layout matches idx*9
  const float* ps = psi + (size_t)(co * CI + ci) * 9;
  const float* m  = mu  + (size_t)(co * CI + ci) * 9;
  float v[9];
#pragma unroll
  for (int p = 0; p < 9; ++p) v[p] = e[p] * __expf(ps[p]) + m[p];
  __bf16* w = wt + ((size_t)b * 9 * CO + co) * CI + ci;
#pragma unroll
  for (int p = 0; p < 9; ++p) w[(size_t)p * CO * CI] = (__bf16)v[p];
}

// ---------------------------------------------------------------------------
// Prep 2a: zero the padded border of inp_t.
// ---------------------------------------------------------------------------
__global__ void border_zero(__bf16* __restrict__ it) {
  int cid = blockIdx.x * 256 + threadIdx.x;
  int pid = cid >> 4;        // border pixel id 0..7295
  int chunk = cid & 15;
  int b = pid / 228;
  int e = pid - b * 228;
  int ph, pw;
  if (e < 58)       { ph = 0;       pw = e; }
  else if (e < 116) { ph = 57;      pw = e - 58; }
  else if (e < 172) { ph = e - 115; pw = 0; }
  else              { ph = e - 171; pw = 57; }
  f32x4 z = {0.f, 0.f, 0.f, 0.f};
  *(f32x4*)&it[((size_t)b * PPIX + ph * PH + pw) * CI + chunk * 8] = z;
}

// ---------------------------------------------------------------------------
// Prep 2b: inp_t[b][(ih+1)*58+(iw+1)][ci] = bf16(input[b][ci][ih][iw])
// ---------------------------------------------------------------------------
__global__ void transpose_pad(const float* __restrict__ in, __bf16* __restrict__ it) {
  __shared__ __align__(16) __bf16 T[64][136];
  int tid = threadIdx.x;
  int p0 = blockIdx.x * 64;
  int b  = blockIdx.y;
  const float* src = in + (size_t)b * CI * NPIX;
#pragma unroll
  for (int j = 0; j < 8; ++j) {
    int c = j * 256 + tid;
    int ci = c >> 4, xc = c & 15;
    float4 v = *(const float4*)(src + (size_t)ci * NPIX + p0 + xc * 4);
    T[xc * 4 + 0][ci] = (__bf16)v.x;
    T[xc * 4 + 1][ci] = (__bf16)v.y;
    T[xc * 4 + 2][ci] = (__bf16)v.z;
    T[xc * 4 + 3][ci] = (__bf16)v.w;
  }
  __syncthreads();
  __bf16* dstb = it + (size_t)b * PPIX * CI;
#pragma unroll
  for (int j = 0; j < 4; ++j) {
    int c = j * 256 + tid;
    int pl = c >> 4, xc = c & 15;
    int pix = p0 + pl;
    int oh = pix / 56, ow = pix - oh * 56;
    int ppix = (oh + 1) * PH + (ow + 1);
    *(f32x4*)&dstb[(size_t)ppix * CI + xc * 8] = *(const f32x4*)&T[pl][xc * 8];
  }
}

// ---------------------------------------------------------------------------
// GEMM, barrier-free: fragments loaded DIRECTLY global -> VGPR (both A and B
// are k(=ci)-contiguous 16B per lane), 2-deep register software pipeline.
// No LDS, no __syncthreads in the K-loop -> fine-grained vmcnt overlap.
// 36 K-steps: s = p*4 + ci-slice, p in [0,9), ci0 = (s&3)*32.
// ---------------------------------------------------------------------------
__device__ __forceinline__ void load_frags(
    const __bf16* __restrict__ wtb, const __bf16* __restrict__ itb,
    int s, int quad8,
    int ab0, int ab1, int ab2, int ab3,
    int br0, int br1, int br2, int br3,
    bf16x8 a[4], bf16x8 b[4]) {
  int p   = s >> 2;
  int ci0 = (s & 3) << 5;
  int kh  = (p * 11) >> 5;           // p/3 for p<9
  int kw  = p - kh * 3;
  int aoff = p * (CO * CI) + ci0 + quad8;
  int boff = (kh * PH + kw - (PH + 1)) * CI + ci0 + quad8;
  a[0] = *(const bf16x8*)(wtb + ab0 + aoff);
  a[1] = *(const bf16x8*)(wtb + ab1 + aoff);
  a[2] = *(const bf16x8*)(wtb + ab2 + aoff);
  a[3] = *(const bf16x8*)(wtb + ab3 + aoff);
  b[0] = *(const bf16x8*)(itb + br0 + boff);
  b[1] = *(const bf16x8*)(itb + br1 + boff);
  b[2] = *(const bf16x8*)(itb + br2 + boff);
  b[3] = *(const bf16x8*)(itb + br3 + boff);
}

__device__ __forceinline__ void do_mfma(const bf16x8 a[4], const bf16x8 b[4],
                                        f32x4 acc[4][4]) {
#pragma unroll
  for (int mf = 0; mf < 4; ++mf)
#pragma unroll
    for (int nf = 0; nf < 4; ++nf)
      acc[mf][nf] = __builtin_amdgcn_mfma_f32_16x16x32_bf16(
          a[mf], b[nf], acc[mf][nf], 0, 0, 0);
}

__global__ __launch_bounds__(256) void bconv_gemm(
    const __bf16* __restrict__ wt,   // [b][9][128 co][128 ci]
    const __bf16* __restrict__ it,   // [b][3364 pix][128 ci]
    float* __restrict__ out) {       // [b][128 co][3136 n]
  const int tid  = threadIdx.x;
  const int w    = tid >> 6;
  const int lane = tid & 63;
  const int quad = lane >> 4;
  const int l15  = lane & 15;
  const int b  = blockIdx.y;
  const int nt = blockIdx.x;
  const int wm = (w >> 1) * 64;
  const int wn = (w & 1) * 64;
  const int quad8 = quad * 8;

  // Per-lane A row bases (element offsets into wt's [co][ci] slab):
  const int ab0 = (wm +  0 + l15) * CI;
  const int ab1 = (wm + 16 + l15) * CI;
  const int ab2 = (wm + 32 + l15) * CI;
  const int ab3 = (wm + 48 + l15) * CI;

  // Per-lane B row bases: padded-pixel(center-tap) * CI for n = nt*128+wn+nf*16+l15
  int br[4];
#pragma unroll
  for (int nf = 0; nf < 4; ++nf) {
    int n = nt * 128 + wn + nf * 16 + l15;
    if (n > NPIX - 1) n = NPIX - 1;            // tail clamp (masked at store)
    int oh = n / 56;
    int ow = n - oh * 56;
    br[nf] = ((oh + 1) * PH + (ow + 1)) * CI;
  }

  const __bf16* wtb = wt + (size_t)b * 9 * CO * CI;
  const __bf16* itb = it + (size_t)b * PPIX * CI;

  f32x4 acc[4][4] = {};
  bf16x8 a0[4], b0[4], a1[4], b1[4];

  load_frags(wtb, itb, 0, quad8, ab0, ab1, ab2, ab3, br[0], br[1], br[2], br[3], a0, b0);
  for (int s = 0; s < 34; s += 2) {
    load_frags(wtb, itb, s + 1, quad8, ab0, ab1, ab2, ab3, br[0], br[1], br[2], br[3], a1, b1);
    do_mfma(a0, b0, acc);
    load_frags(wtb, itb, s + 2, quad8, ab0, ab1, ab2, ab3, br[0], br[1], br[2], br[3], a0, b0);
    do_mfma(a1, b1, acc);
  }
  load_frags(wtb, itb, 35, quad8, ab0, ab1, ab2, ab3, br[0], br[1], br[2], br[3], a1, b1);
  do_mfma(a0, b0, acc);
  do_mfma(a1, b1, acc);

  // Epilogue: C row=co (quad*4+reg), col=n (l15).
  float* ob = out + (size_t)b * CO * NPIX;
#pragma unroll
  for (int mf = 0; mf < 4; ++mf) {
#pragma unroll
    for (int nf = 0; nf < 4; ++nf) {
      int n = nt * 128 + wn + nf * 16 + l15;
      if (n < NPIX) {
#pragma unroll
        for (int r = 0; r < 4; ++r) {
          int co = wm + mf * 16 + quad * 4 + r;
          ob[(size_t)co * NPIX + n] = acc[mf][nf][r];
        }
      }
    }
  }
}

// ---------------------------------------------------------------------------
extern "C" void kernel_launch(void* const* d_in, const int* in_sizes, int n_in,
                              void* d_out, int out_size, void* d_ws, size_t ws_size,
                              hipStream_t stream) {
  const float* inp = (const float*)d_in[0];   // [32,128,56,56]
  const float* eps = (const float*)d_in[1];   // [32,128,128,3,3]
  const float* psi = (const float*)d_in[2];   // [128,128,3,3]
  const float* mu  = (const float*)d_in[3];   // [128,128,3,3]

  // ws layout: wt (9,437,184 B) | inp_t (27,557,888 B)
  __bf16* wt = (__bf16*)d_ws;
  __bf16* it = (__bf16*)((char*)d_ws + 9437184);

  prep_weights<<<2048, 256, 0, stream>>>(eps, psi, mu, wt);
  border_zero<<<456, 256, 0, stream>>>(it);
  transpose_pad<<<dim3(49, 32), 256, 0, stream>>>(inp, it);
  bconv_gemm<<<dim3(NT, 32), 256, 0, stream>>>(wt, it, (float*)d_out);
}

// Round 3
// 209.955 us; speedup vs baseline: 1.1949x; 1.1949x over previous
//
#include <hip/hip_runtime.h>
#include <hip/hip_bf16.h>

// Problem constants
#define CO    128
#define CI    128
#define NPIX  3136   // 56*56
#define PH    58
#define PPIX  3364   // 58*58

typedef __bf16 bf16x8 __attribute__((ext_vector_type(8)));
typedef float  f32x4  __attribute__((ext_vector_type(4)));

__device__ __forceinline__ void glds16(const void* g, void* l) {
  __builtin_amdgcn_global_load_lds(
      (const __attribute__((address_space(1))) void*)g,
      (__attribute__((address_space(3))) void*)l, 16, 0, 0);
}

// ---------------------------------------------------------------------------
// Fused prep: [0,2048) weights | [2048,2504) border zero | [2504,4072) transpose.
// One dispatch -> the three independent phases overlap across CUs.
// ---------------------------------------------------------------------------
__global__ void prep_all(const float* __restrict__ in,
                         const float* __restrict__ eps,
                         const float* __restrict__ psi,
                         const float* __restrict__ mu,
                         __bf16* __restrict__ wt,
                         __bf16* __restrict__ it) {
  __shared__ __align__(16) __bf16 T[64][136];
  const int bx = blockIdx.x, tid = threadIdx.x;

  if (bx < 2048) {
    // weights: one thread per (b,co,ci), 9 contiguous floats each side.
    int idx = bx * 256 + tid;               // = (b*CO+co)*CI+ci
    int ci = idx & 127;
    int co = (idx >> 7) & 127;
    int b  = idx >> 14;
    const float* e  = eps + (size_t)idx * 9;
    const float* ps = psi + (size_t)(co * CI + ci) * 9;
    const float* m  = mu  + (size_t)(co * CI + ci) * 9;
    float v[9];
#pragma unroll
    for (int p = 0; p < 9; ++p) v[p] = e[p] * __expf(ps[p]) + m[p];
    __bf16* w = wt + ((size_t)b * 9 * CO + co) * CI + ci;
#pragma unroll
    for (int p = 0; p < 9; ++p) w[(size_t)p * CO * CI] = (__bf16)v[p];
  } else if (bx < 2504) {
    // border zero: 228 border pixels/batch, 16 chunks of 16B each.
    int cid = (bx - 2048) * 256 + tid;
    int pid = cid >> 4;
    int chunk = cid & 15;
    int b = pid / 228;
    int e = pid - b * 228;
    int ph, pw;
    if (e < 58)       { ph = 0;       pw = e; }
    else if (e < 116) { ph = 57;      pw = e - 58; }
    else if (e < 172) { ph = e - 115; pw = 0; }
    else              { ph = e - 171; pw = 57; }
    f32x4 z = {0.f, 0.f, 0.f, 0.f};
    *(f32x4*)&it[((size_t)b * PPIX + ph * PH + pw) * CI + chunk * 8] = z;
  } else {
    // transpose+pad: inp_t[b][(ih+1)*58+(iw+1)][ci] = bf16(input[b][ci][ih][iw])
    int tx = bx - 2504;
    int b  = tx / 49;
    int p0 = (tx - b * 49) * 64;
    const float* src = in + (size_t)b * CI * NPIX;
#pragma unroll
    for (int jj = 0; jj < 8; ++jj) {
      int c = jj * 256 + tid;
      int ci = c >> 4, xc = c & 15;
      float4 v = *(const float4*)(src + (size_t)ci * NPIX + p0 + xc * 4);
      T[xc * 4 + 0][ci] = (__bf16)v.x;
      T[xc * 4 + 1][ci] = (__bf16)v.y;
      T[xc * 4 + 2][ci] = (__bf16)v.z;
      T[xc * 4 + 3][ci] = (__bf16)v.w;
    }
    __syncthreads();
    __bf16* dstb = it + (size_t)b * PPIX * CI;
#pragma unroll
    for (int jj = 0; jj < 4; ++jj) {
      int c = jj * 256 + tid;
      int pl = c >> 4, xc = c & 15;
      int pix = p0 + pl;
      int oh = pix / 56, ow = pix - oh * 56;
      int ppix = (oh + 1) * PH + (ow + 1);
      *(f32x4*)&dstb[(size_t)ppix * CI + xc * 8] = *(const f32x4*)&T[pl][xc * 8];
    }
  }
}

// ---------------------------------------------------------------------------
// GEMM: 64co x 128n tile per block (CO split in 2 -> 1600 blocks, 6.25/CU),
// BK=32, double-buffered LDS staging via global_load_lds, ONE barrier/step:
//   barrier; stage(s+1 -> buf^1); compute(s, buf)
// XCD swizzle: linear%8 == batch%8 so each batch's 50 blocks share an XCD L2.
// 4 waves, each 32co x 64n (2x4 frags of 16x16x32 bf16).
// ---------------------------------------------------------------------------
__global__ __launch_bounds__(256) void bconv_gemm(
    const __bf16* __restrict__ wt,   // [b][9][128 co][128 ci]
    const __bf16* __restrict__ it,   // [b][3364 pix][128 ci]
    float* __restrict__ out) {       // [b][128 co][3136 n]
  __shared__ __align__(16) __bf16 As[2][2048];   // [buf][ko(4)][co(64)][8]
  __shared__ __align__(16) __bf16 Bs[2][4096];   // [buf][ko(4)][n(128)][8]
  const int tid  = threadIdx.x;
  const int w    = tid >> 6;
  const int lane = tid & 63;
  const int quad = lane >> 4;
  const int l15  = lane & 15;

  // XCD-affinity decode: lin = j*8 + (b%8); j = (b/8)*50 + t; t = cb*25 + nt
  const int lin = blockIdx.x;
  const int x = lin & 7;
  const int j = lin >> 3;
  const int g = j / 50;
  const int t = j - g * 50;
  const int b  = g * 8 + x;
  const int cb = t / 25;
  const int nt = t - cb * 25;

  const int wm = (w & 1) * 32;    // co within 64-row half
  const int wn = (w >> 1) * 64;   // n within 128-col tile

  // B staging bases: padded center-tap pixel * CI for rows q*64+lane.
  int pixb[2];
#pragma unroll
  for (int q = 0; q < 2; ++q) {
    int n = nt * 128 + q * 64 + lane;
    if (n > NPIX - 1) n = NPIX - 1;         // tail clamp (masked at store)
    int oh = n / 56;
    int ow = n - oh * 56;
    pixb[q] = ((oh + 1) * PH + (ow + 1)) * CI;
  }

  const __bf16* wtb = wt + ((size_t)b * 9 * CO + cb * 64) * CI;
  const __bf16* itb = it + (size_t)b * PPIX * CI;

  f32x4 acc[2][4] = {};

  // stage step s into buffer `buf`: wave w covers ko=w; A 1 glds + B 2 glds.
  auto stage = [&](int s, int buf) {
    int p   = s >> 2;
    int ci0 = (s & 3) << 5;
    int kh  = (p * 11) >> 5;                // p/3 for p<9
    int kw  = p - kh * 3;
    int poff = (kh * PH + kw - (PH + 1)) * CI;
    const __bf16* ap = wtb + p * (CO * CI) + ci0 + w * 8;
    glds16(ap + lane * CI, &As[buf][w * 512]);
    const __bf16* bp = itb + poff + ci0 + w * 8;
    glds16(bp + pixb[0], &Bs[buf][w * 1024]);
    glds16(bp + pixb[1], &Bs[buf][w * 1024 + 512]);
  };

  stage(0, 0);
  for (int s = 0; s < 36; ++s) {
    const int buf = s & 1;
    // barrier: (a) stage(s) drained+visible; (b) compute(s-1) on buf^1 done,
    // so staging into buf^1 below is safe. ONE barrier per K-step.
    __syncthreads();
    if (s < 35) stage(s + 1, buf ^ 1);
    bf16x8 af[2], bfr[4];
#pragma unroll
    for (int mf = 0; mf < 2; ++mf)
      af[mf] = *(const bf16x8*)&As[buf][quad * 512 + (wm + mf * 16 + l15) * 8];
#pragma unroll
    for (int nf = 0; nf < 4; ++nf)
      bfr[nf] = *(const bf16x8*)&Bs[buf][quad * 1024 + (wn + nf * 16 + l15) * 8];
#pragma unroll
    for (int mf = 0; mf < 2; ++mf)
#pragma unroll
      for (int nf = 0; nf < 4; ++nf)
        acc[mf][nf] = __builtin_amdgcn_mfma_f32_16x16x32_bf16(
            af[mf], bfr[nf], acc[mf][nf], 0, 0, 0);
  }

  // Epilogue: C row=co (quad*4+reg), col=n (l15).
  float* ob = out + (size_t)b * CO * NPIX;
#pragma unroll
  for (int mf = 0; mf < 2; ++mf) {
#pragma unroll
    for (int nf = 0; nf < 4; ++nf) {
      int n = nt * 128 + wn + nf * 16 + l15;
      if (n < NPIX) {
#pragma unroll
        for (int r = 0; r < 4; ++r) {
          int co = cb * 64 + wm + mf * 16 + quad * 4 + r;
          ob[(size_t)co * NPIX + n] = acc[mf][nf][r];
        }
      }
    }
  }
}

// ---------------------------------------------------------------------------
extern "C" void kernel_launch(void* const* d_in, const int* in_sizes, int n_in,
                              void* d_out, int out_size, void* d_ws, size_t ws_size,
                              hipStream_t stream) {
  const float* inp = (const float*)d_in[0];   // [32,128,56,56]
  const float* eps = (const float*)d_in[1];   // [32,128,128,3,3]
  const float* psi = (const float*)d_in[2];   // [128,128,3,3]
  const float* mu  = (const float*)d_in[3];   // [128,128,3,3]

  // ws layout: wt (9,437,184 B) | inp_t (27,557,888 B)
  __bf16* wt = (__bf16*)d_ws;
  __bf16* it = (__bf16*)((char*)d_ws + 9437184);

  prep_all<<<4072, 256, 0, stream>>>(inp, eps, psi, mu, wt, it);
  bconv_gemm<<<1600, 256, 0, stream>>>(wt, it, (float*)d_out);
}

// Round 4
// 159.384 us; speedup vs baseline: 1.5741x; 1.3173x over previous
//
#include <hip/hip_runtime.h>
#include <hip/hip_bf16.h>

// Problem constants
#define CO    128
#define CI    128
#define NPIX  3136   // 56*56
#define PH    58
#define PPIX  3364   // 58*58
#define HPX   232    // halo pixels per block: 4 padded rows * 58
#define SROW  272    // LDS bytes per halo pixel: 256 data + 16 pad (bank balance)

typedef __bf16 bf16x8 __attribute__((ext_vector_type(8)));
typedef float  f32x4  __attribute__((ext_vector_type(4)));

// ---------------------------------------------------------------------------
// Fused prep: [0,2048) weights | [2048,2504) border zero | [2504,4072) transpose.
// ---------------------------------------------------------------------------
__global__ void prep_all(const float* __restrict__ in,
                         const float* __restrict__ eps,
                         const float* __restrict__ psi,
                         const float* __restrict__ mu,
                         __bf16* __restrict__ wt,
                         __bf16* __restrict__ it) {
  __shared__ __align__(16) __bf16 T[64][136];
  const int bx = blockIdx.x, tid = threadIdx.x;

  if (bx < 2048) {
    int idx = bx * 256 + tid;               // = (b*CO+co)*CI+ci
    int ci = idx & 127;
    int co = (idx >> 7) & 127;
    const float* e  = eps + (size_t)idx * 9;
    const float* ps = psi + (size_t)(co * CI + ci) * 9;
    const float* m  = mu  + (size_t)(co * CI + ci) * 9;
    float v[9];
#pragma unroll
    for (int p = 0; p < 9; ++p) v[p] = e[p] * __expf(ps[p]) + m[p];
    int b = idx >> 14;
    __bf16* w = wt + ((size_t)b * 9 * CO + co) * CI + ci;
#pragma unroll
    for (int p = 0; p < 9; ++p) w[(size_t)p * CO * CI] = (__bf16)v[p];
  } else if (bx < 2504) {
    int cid = (bx - 2048) * 256 + tid;
    int pid = cid >> 4;
    int chunk = cid & 15;
    int b = pid / 228;
    int e = pid - b * 228;
    int ph, pw;
    if (e < 58)       { ph = 0;       pw = e; }
    else if (e < 116) { ph = 57;      pw = e - 58; }
    else if (e < 172) { ph = e - 115; pw = 0; }
    else              { ph = e - 171; pw = 57; }
    f32x4 z = {0.f, 0.f, 0.f, 0.f};
    *(f32x4*)&it[((size_t)b * PPIX + ph * PH + pw) * CI + chunk * 8] = z;
  } else {
    int tx = bx - 2504;
    int b  = tx / 49;
    int p0 = (tx - b * 49) * 64;
    const float* src = in + (size_t)b * CI * NPIX;
#pragma unroll
    for (int jj = 0; jj < 8; ++jj) {
      int c = jj * 256 + tid;
      int ci = c >> 4, xc = c & 15;
      float4 v = *(const float4*)(src + (size_t)ci * NPIX + p0 + xc * 4);
      T[xc * 4 + 0][ci] = (__bf16)v.x;
      T[xc * 4 + 1][ci] = (__bf16)v.y;
      T[xc * 4 + 2][ci] = (__bf16)v.z;
      T[xc * 4 + 3][ci] = (__bf16)v.w;
    }
    __syncthreads();
    __bf16* dstb = it + (size_t)b * PPIX * CI;
#pragma unroll
    for (int jj = 0; jj < 4; ++jj) {
      int c = jj * 256 + tid;
      int pl = c >> 4, xc = c & 15;
      int pix = p0 + pl;
      int oh = pix / 56, ow = pix - oh * 56;
      int ppix = (oh + 1) * PH + (ow + 1);
      *(f32x4*)&dstb[(size_t)ppix * CI + xc * 8] = *(const f32x4*)&T[pl][xc * 8];
    }
  }
}

// ---------------------------------------------------------------------------
// GEMM/conv, barrier-free K-loop ("B-stationary halo"):
//   block = 128 co x 112 n (2 full image rows), 4 waves of 32co x 112n.
//   Prologue: stage the 4-row halo (232 px x 256B, contiguous in it[]) into
//   LDS once (272B padded rows -> balanced banks), ONE __syncthreads.
//   K-loop (9 taps x 4 ci-slices = 36 steps): B from LDS at tap offsets,
//   A direct global->VGPR with 1-step register prefetch. NO barriers.
//   Grid 28 tiles x 32 batch = 896 blocks; LDS 63104B -> 2 blocks/CU.
// ---------------------------------------------------------------------------
__global__ __launch_bounds__(256) void bconv_gemm(
    const __bf16* __restrict__ wt,   // [b][9][128 co][128 ci]
    const __bf16* __restrict__ it,   // [b][3364 pix][128 ci]
    float* __restrict__ out) {       // [b][128 co][3136 n]
  __shared__ __align__(16) char Bsh[HPX * SROW];   // 63104 B
  const int tid  = threadIdx.x;
  const int w    = tid >> 6;
  const int lane = tid & 63;
  const int quad = lane >> 4;
  const int l15  = lane & 15;

  // Decode: lin = x + 8*(tile*4 + bhi); b = x + 8*bhi  -> same-b blocks share an XCD
  const int lin = blockIdx.x;
  const int x   = lin & 7;
  const int j   = lin >> 3;          // 0..111
  const int bhi = j & 3;
  const int tile = j >> 2;           // 0..27
  const int b   = x + 8 * bhi;
  const int oh0 = tile * 2;          // first output row of this tile

  // ---- prologue: stage halo (padded rows oh0..oh0+3, contiguous) ----
  const __bf16* hsrc = it + ((size_t)b * PPIX + oh0 * PH) * CI;
#pragma unroll
  for (int i = 0; i < 15; ++i) {
    int idx = i * 256 + tid;                 // 16B chunk id, 3712 total
    if (idx < HPX * 16) {
      int px = idx >> 4, sub = idx & 15;
      f32x4 v = *(const f32x4*)(hsrc + (size_t)idx * 8);
      *(f32x4*)&Bsh[px * SROW + sub * 16] = v;
    }
  }
  __syncthreads();

  // ---- per-lane B fragment LDS byte-bases (tap (0,0), ci-slice 0) ----
  int bbase[7];
#pragma unroll
  for (int nf = 0; nf < 7; ++nf) {
    int n = nf * 16 + l15;                   // 0..111
    int r = (n >= 56) ? 1 : 0;
    int c = n - r * 56;
    bbase[nf] = (r * PH + c) * SROW + quad * 16;
  }

  // ---- per-lane A global bases (elements) ----
  const int co0 = w * 32;
  const __bf16* wtb = wt + (size_t)b * 9 * CO * CI;
  const int ab0 = (co0 +      l15) * CI + quad * 8;
  const int ab1 = (co0 + 16 + l15) * CI + quad * 8;

  f32x4 acc[2][7] = {};
  bf16x8 acur[2], anxt[2];
  acur[0] = *(const bf16x8*)(wtb + ab0);
  acur[1] = *(const bf16x8*)(wtb + ab1);

#pragma unroll
  for (int s = 0; s < 36; ++s) {
    const int p   = s >> 2;
    const int ci0 = (s & 3) << 5;
    // prefetch A for step s+1 (register double-buffer; no barrier anywhere)
    if (s < 35) {
      const int pn   = (s + 1) >> 2;
      const int ci0n = ((s + 1) & 3) << 5;
      const __bf16* ap = wtb + pn * (CO * CI) + ci0n;
      anxt[0] = *(const bf16x8*)(ap + ab0);
      anxt[1] = *(const bf16x8*)(ap + ab1);
    }
    const int kh = p / 3, kw = p - kh * 3;
    const int tapb = (kh * PH + kw) * SROW + ci0 * 2;   // compile-time (unrolled)
#pragma unroll
    for (int nf = 0; nf < 7; ++nf) {
      bf16x8 bfr = *(const bf16x8*)&Bsh[bbase[nf] + tapb];
      acc[0][nf] = __builtin_amdgcn_mfma_f32_16x16x32_bf16(acur[0], bfr, acc[0][nf], 0, 0, 0);
      acc[1][nf] = __builtin_amdgcn_mfma_f32_16x16x32_bf16(acur[1], bfr, acc[1][nf], 0, 0, 0);
    }
    acur[0] = anxt[0];
    acur[1] = anxt[1];
  }

  // ---- epilogue: C col(l15)=n, row(quad*4+r)=co; n_global = oh0*56 + n ----
  float* ob = out + (size_t)b * CO * NPIX + oh0 * 56;
#pragma unroll
  for (int mf = 0; mf < 2; ++mf) {
#pragma unroll
    for (int nf = 0; nf < 7; ++nf) {
#pragma unroll
      for (int r = 0; r < 4; ++r) {
        int co = co0 + mf * 16 + quad * 4 + r;
        ob[(size_t)co * NPIX + nf * 16 + l15] = acc[mf][nf][r];
      }
    }
  }
}

// ---------------------------------------------------------------------------
extern "C" void kernel_launch(void* const* d_in, const int* in_sizes, int n_in,
                              void* d_out, int out_size, void* d_ws, size_t ws_size,
                              hipStream_t stream) {
  const float* inp = (const float*)d_in[0];   // [32,128,56,56]
  const float* eps = (const float*)d_in[1];   // [32,128,128,3,3]
  const float* psi = (const float*)d_in[2];   // [128,128,3,3]
  const float* mu  = (const float*)d_in[3];   // [128,128,3,3]

  // ws layout: wt (9,437,184 B) | inp_t (27,557,888 B)
  __bf16* wt = (__bf16*)d_ws;
  __bf16* it = (__bf16*)((char*)d_ws + 9437184);

  prep_all<<<4072, 256, 0, stream>>>(inp, eps, psi, mu, wt, it);
  bconv_gemm<<<896, 256, 0, stream>>>(wt, it, (float*)d_out);
}